// Round 1
// 693.102 us; speedup vs baseline: 1.6133x; 1.6133x over previous
//
#include <hip/hip_runtime.h>
#include <stdint.h>
#include <math.h>

#define V_SZ 100000
#define D_SZ 512
#define B_SZ 1024
#define C_SZ 20
#define NEG 64
#define NB 2048
#define CAP 512
// -log(256): expected candidates/row = e^{-TCUT} * sum(sample_prob) = 256.
#define TCUT -5.5451774f

// ---- Cephes f32 log matching XLA-CPU GenerateVF32Log (FMA polynomial chain,
// separate mul/add tail). fp contract(off) so hipcc can't re-fuse differently.
__device__ __forceinline__ float xla_logf(float xin) {
#pragma clang fp contract(off)
  float x = fmaxf(xin, 1.17549435e-38f);            // clamp to min normal
  uint32_t bits = __float_as_uint(x);
  float e = (float)((int)(bits >> 23) - 127) + 1.0f;
  float m = __uint_as_float((bits & 0x807fffffu) | 0x3f000000u);  // [0.5,1)
  bool lt = m < 0.707106781186547524f;
  float tmp = lt ? m : 0.0f;
  m = m - 1.0f;
  e = e - (lt ? 1.0f : 0.0f);
  m = m + tmp;
  float z = m * m;
  float y = 7.0376836292E-2f;
  y = fmaf(y, m, -1.1514610310E-1f);
  y = fmaf(y, m, 1.1676998740E-1f);
  y = fmaf(y, m, -1.2420140846E-1f);
  y = fmaf(y, m, 1.4249322787E-1f);
  y = fmaf(y, m, -1.6668057665E-1f);
  y = fmaf(y, m, 2.0000714765E-1f);
  y = fmaf(y, m, -2.4999993993E-1f);
  y = fmaf(y, m, 3.3333331174E-1f);
  y = y * m;
  y = y * z;
  y = y + e * (-2.12194440e-4f);
  y = y - z * 0.5f;
  x = m + y;
  x = x + e * 0.693359375f;
  return x;
}

// ---- Threefry-2x32, 20 rounds, key = jax.random.key(42) -> (0, 42). ----
__device__ __forceinline__ void threefry2x32(uint32_t x0, uint32_t x1,
                                             uint32_t& o0, uint32_t& o1) {
  const uint32_t ks1 = 42u, ks2 = 0x1BD11BF0u;  // 0 ^ 42 ^ 0x1BD11BDA
#define TFR(r) { x0 += x1; x1 = (x1 << (r)) | (x1 >> (32 - (r))); x1 ^= x0; }
  x0 += 0u; x1 += ks1;
  TFR(13) TFR(15) TFR(26) TFR(6)
  x0 += ks1; x1 += ks2 + 1u;
  TFR(17) TFR(29) TFR(16) TFR(24)
  x0 += ks2; x1 += 0u + 2u;
  TFR(13) TFR(15) TFR(26) TFR(6)
  x0 += 0u; x1 += ks1 + 3u;
  TFR(17) TFR(29) TFR(16) TFR(24)
  x0 += ks1; x1 += ks2 + 4u;
  TFR(13) TFR(15) TFR(26) TFR(6)
  x0 += ks2; x1 += 0u + 5u;
#undef TFR
  o0 = x0; o1 = x1;
}

// PARTITIONABLE threefry (modern JAX default): element i uses 64-bit counter i
// -> block input (hi,lo) = (0, i); 32-bit draw is out0 ^ out1.
__device__ __forceinline__ uint32_t tf_bits_partitionable(uint32_t i) {
  uint32_t o0, o1;
  threefry2x32(0u, i, o0, o1);
  return o0 ^ o1;
}

// u = (mbits>0) ? mbits*2^-23 : FLT_MIN ; g = -log(-log(u)).
__device__ __forceinline__ float gumbel_from_bits(uint32_t bits) {
#pragma clang fp contract(off)
  float f = __uint_as_float((bits >> 9) | 0x3f800000u) - 1.0f;
  float u = (bits >> 9) ? f : 1.17549435e-38f;
  return -xla_logf(-xla_logf(u));
}

// Single helper so rounding is identical everywhere.
__device__ __forceinline__ float score_one(uint32_t i, float lpv) {
#pragma clang fp contract(off)
  return lpv + gumbel_from_bits(tf_bits_partitionable(i));
}

// Per-vocab mantissa threshold: mbits < thr[v]  =>  score(v) < TCUT, certainly.
// thr = floor(exp(-exp(-(TCUT - lp[v]))) * 2^23) - 128 slack.
// Near the cut dg/du >= ~220 so 128 mantissa steps ≙ δg >= 3.4e-3, vs <= ~3e-5
// total float error in the expf / xla_logf chains -> 100x safety margin.
__global__ __launch_bounds__(256) void compute_thr(const float* __restrict__ sp,
                                                   uint32_t* __restrict__ thr) {
  int v = blockIdx.x * 256 + threadIdx.x;
  if (v >= V_SZ) return;
  float lpv = xla_logf(sp[v]);
  float need = TCUT - lpv;                 // >= ~5.4 for this distribution
  float u = expf(-expf(-need));            // ideal inverse-Gumbel CDF at need
  int m = (int)floorf(u * 8388608.0f) - 128;
  thr[v] = (uint32_t)(m < 0 ? 0 : m);
}

// One block per batch row. Filtered single pass + exact rank; exact-score
// guard falls back to the proven histogram path (never taken in practice).
__global__ __launch_bounds__(256) void select_negs(const float* __restrict__ sp,
                                                   const uint32_t* __restrict__ thr,
                                                   int* __restrict__ negidx) {
  __shared__ uint32_t hist[NB];
  __shared__ float cs[CAP];
  __shared__ int   ci[CAP];
  __shared__ int   cnt;
  __shared__ int   cnt_hi;
  __shared__ int   cut;

  const int b = blockIdx.x;                             // 0..1023
  const uint32_t base = (uint32_t)b * (uint32_t)V_SZ;   // < 2^32

  if (threadIdx.x == 0) { cnt = 0; cnt_hi = 0; }
  __syncthreads();

  // Main pass: threefry + integer compare only. ~0.26% of elements take the
  // expensive (exact-score) path.
  for (int v = threadIdx.x; v < V_SZ; v += 256) {
    uint32_t bits = tf_bits_partitionable(base + (uint32_t)v);
    if ((bits >> 9) >= thr[v]) {
      float s = xla_logf(sp[v]) + gumbel_from_bits(bits);  // == score_one
      int k = atomicAdd(&cnt, 1);
      if (k < CAP) { cs[k] = s; ci[k] = v; }
      if (s >= TCUT) atomicAdd(&cnt_hi, 1);
    }
  }
  __syncthreads();

  // Guard: >=64 collected with exact s >= TCUT  =>  true 64th-best >= TCUT
  // => every true top-64 element passed the (conservative) filter and was
  // stored (cnt <= CAP). Ranks among the collected superset then equal
  // global ranks for all written entries.
  if (cnt <= CAP && cnt_hi >= NEG) {
    int n = cnt;
    for (int i = threadIdx.x; i < n; i += 256) {
      float si = cs[i]; int vi = ci[i];
      int rank = 0;
      for (int j = 0; j < n; ++j) {
        float sj = cs[j];
        rank += (sj > si) || (sj == si && ci[j] < vi);
      }
      if (rank < NEG) negidx[b * NEG + rank] = vi;
    }
    return;
  }

  // ---- Fallback: original exact histogram path (lp recomputed inline). ----
  const float LO = -28.0f, INVW = 51.2f;                // 2048 bins over [-28,12)
  for (int i = threadIdx.x; i < NB; i += 256) hist[i] = 0u;
  if (threadIdx.x == 0) cnt = 0;
  __syncthreads();

  for (int v = threadIdx.x; v < V_SZ; v += 256) {
    float s = score_one(base + (uint32_t)v, xla_logf(sp[v]));
    int bin = min(NB - 1, max(0, (int)((s - LO) * INVW)));
    atomicAdd(&hist[bin], 1u);
  }
  __syncthreads();

  if (threadIdx.x == 0) {
    uint32_t acc = 0; int c = NB - 1;
    for (; c > 0; --c) { acc += hist[c]; if (acc >= (uint32_t)NEG) break; }
    cut = c;
  }
  __syncthreads();
  const int cutb = cut;

  for (int v = threadIdx.x; v < V_SZ; v += 256) {
    float s = score_one(base + (uint32_t)v, xla_logf(sp[v]));
    int bin = min(NB - 1, max(0, (int)((s - LO) * INVW)));
    if (bin >= cutb) {
      int k = atomicAdd(&cnt, 1);
      if (k < CAP) { cs[k] = s; ci[k] = v; }
    }
  }
  __syncthreads();

  int n = min(cnt, CAP);
  for (int i = threadIdx.x; i < n; i += 256) {
    float si = cs[i]; int vi = ci[i];
    int rank = 0;
    for (int j = 0; j < n; ++j) {
      float sj = cs[j];
      rank += (sj > si) || (sj == si && ci[j] < vi);
    }
    if (rank < NEG) negidx[b * NEG + rank] = vi;
  }
}

// One block per batch row: center fragment in registers, one wave per item,
// 4 items in flight per wave (8 outstanding float4 loads) to hide HBM latency.
__global__ __launch_bounds__(256) void dots(const int* __restrict__ center_ids,
                                            const int* __restrict__ context_ids,
                                            const float* __restrict__ Wcen,
                                            const float* __restrict__ Wctx,
                                            const int* __restrict__ negidx,
                                            float* __restrict__ out) {
  __shared__ float cen[D_SZ];
  const int b = blockIdx.x;
  const int cid = center_ids[b];
  const float4* crow = (const float4*)(Wcen + (size_t)cid * D_SZ);
  for (int i = threadIdx.x; i < D_SZ / 4; i += 256) ((float4*)cen)[i] = crow[i];
  __syncthreads();

  const int wave = threadIdx.x >> 6, lane = threadIdx.x & 63;
  const float4 c0 = ((const float4*)cen)[lane * 2];
  const float4 c1 = ((const float4*)cen)[lane * 2 + 1];

  for (int it0 = wave; it0 < C_SZ + NEG; it0 += 16) {
    float4 a0[4], a1[4];
#pragma unroll
    for (int u = 0; u < 4; ++u) {
      int item = it0 + 4 * u;
      if (item < C_SZ + NEG) {
        const float* row;
        if (item < C_SZ) row = Wcen + (size_t)context_ids[b * C_SZ + item] * D_SZ;
        else             row = Wctx + (size_t)negidx[b * NEG + (item - C_SZ)] * D_SZ;
        const float4* r4 = (const float4*)row;
        a0[u] = r4[lane * 2];
        a1[u] = r4[lane * 2 + 1];
      }
    }
#pragma unroll
    for (int u = 0; u < 4; ++u) {
      int item = it0 + 4 * u;
      if (item < C_SZ + NEG) {
        float p = a0[u].x * c0.x + a0[u].y * c0.y + a0[u].z * c0.z + a0[u].w * c0.w +
                  a1[u].x * c1.x + a1[u].y * c1.y + a1[u].z * c1.z + a1[u].w * c1.w;
        for (int off = 32; off; off >>= 1) p += __shfl_xor(p, off, 64);
        if (lane == 0) {
          if (item < C_SZ) out[b * C_SZ + item] = p;
          else out[B_SZ * C_SZ + b * NEG + (item - C_SZ)] = p;
        }
      }
    }
  }
}

extern "C" void kernel_launch(void* const* d_in, const int* in_sizes, int n_in,
                              void* d_out, int out_size, void* d_ws, size_t ws_size,
                              hipStream_t stream) {
  (void)in_sizes; (void)n_in; (void)out_size; (void)ws_size;
  const int*   center_ids  = (const int*)d_in[0];
  const int*   context_ids = (const int*)d_in[1];
  const float* Wcen        = (const float*)d_in[2];
  const float* Wctx        = (const float*)d_in[3];
  const float* sp          = (const float*)d_in[4];
  // d_in[5] = neg_sample (=64), compile-time constant here.

  uint32_t* thr    = (uint32_t*)d_ws;                   // V u32 (400 KB)
  int*      negidx = (int*)((char*)d_ws + 512 * 1024);  // B*64 ints (256 KB)

  compute_thr<<<(V_SZ + 255) / 256, 256, 0, stream>>>(sp, thr);
  select_negs<<<B_SZ,              256, 0, stream>>>(sp, thr, negidx);
  dots       <<<B_SZ,              256, 0, stream>>>(center_ids, context_ids,
                                                     Wcen, Wctx, negidx,
                                                     (float*)d_out);
}

// Round 2
// 654.940 us; speedup vs baseline: 1.7073x; 1.0583x over previous
//
#include <hip/hip_runtime.h>
#include <stdint.h>
#include <math.h>

#define V_SZ 100000
#define D_SZ 512
#define B_SZ 1024
#define C_SZ 20
#define NEG 64
#define NB 2048
#define CAP 512
#define ITEMS (C_SZ + NEG)   // 84
// -log(256): expected candidates/row = e^{-TCUT} * sum(sample_prob) = 256.
#define TCUT -5.5451774f

// ---- Cephes f32 log matching XLA-CPU GenerateVF32Log (FMA polynomial chain,
// separate mul/add tail). fp contract(off) so hipcc can't re-fuse differently.
__device__ __forceinline__ float xla_logf(float xin) {
#pragma clang fp contract(off)
  float x = fmaxf(xin, 1.17549435e-38f);            // clamp to min normal
  uint32_t bits = __float_as_uint(x);
  float e = (float)((int)(bits >> 23) - 127) + 1.0f;
  float m = __uint_as_float((bits & 0x807fffffu) | 0x3f000000u);  // [0.5,1)
  bool lt = m < 0.707106781186547524f;
  float tmp = lt ? m : 0.0f;
  m = m - 1.0f;
  e = e - (lt ? 1.0f : 0.0f);
  m = m + tmp;
  float z = m * m;
  float y = 7.0376836292E-2f;
  y = fmaf(y, m, -1.1514610310E-1f);
  y = fmaf(y, m, 1.1676998740E-1f);
  y = fmaf(y, m, -1.2420140846E-1f);
  y = fmaf(y, m, 1.4249322787E-1f);
  y = fmaf(y, m, -1.6668057665E-1f);
  y = fmaf(y, m, 2.0000714765E-1f);
  y = fmaf(y, m, -2.4999993993E-1f);
  y = fmaf(y, m, 3.3333331174E-1f);
  y = y * m;
  y = y * z;
  y = y + e * (-2.12194440e-4f);
  y = y - z * 0.5f;
  x = m + y;
  x = x + e * 0.693359375f;
  return x;
}

// ---- Threefry-2x32, 20 rounds, key = jax.random.key(42) -> (0, 42). ----
// Rotates via __builtin_rotateleft32 so each is a single v_alignbit_b32.
__device__ __forceinline__ void threefry2x32(uint32_t x0, uint32_t x1,
                                             uint32_t& o0, uint32_t& o1) {
  const uint32_t ks1 = 42u, ks2 = 0x1BD11BF0u;  // 0 ^ 42 ^ 0x1BD11BDA
#define TFR(r) { x0 += x1; x1 = __builtin_rotateleft32(x1, (r)); x1 ^= x0; }
  x0 += 0u; x1 += ks1;
  TFR(13) TFR(15) TFR(26) TFR(6)
  x0 += ks1; x1 += ks2 + 1u;
  TFR(17) TFR(29) TFR(16) TFR(24)
  x0 += ks2; x1 += 0u + 2u;
  TFR(13) TFR(15) TFR(26) TFR(6)
  x0 += 0u; x1 += ks1 + 3u;
  TFR(17) TFR(29) TFR(16) TFR(24)
  x0 += ks1; x1 += ks2 + 4u;
  TFR(13) TFR(15) TFR(26) TFR(6)
  x0 += ks2; x1 += 0u + 5u;
#undef TFR
  o0 = x0; o1 = x1;
}

// PARTITIONABLE threefry (modern JAX default): element i uses 64-bit counter i
// -> block input (hi,lo) = (0, i); 32-bit draw is out0 ^ out1.
__device__ __forceinline__ uint32_t tf_bits_partitionable(uint32_t i) {
  uint32_t o0, o1;
  threefry2x32(0u, i, o0, o1);
  return o0 ^ o1;
}

// u = (mbits>0) ? mbits*2^-23 : FLT_MIN ; g = -log(-log(u)).
__device__ __forceinline__ float gumbel_from_bits(uint32_t bits) {
#pragma clang fp contract(off)
  float f = __uint_as_float((bits >> 9) | 0x3f800000u) - 1.0f;
  float u = (bits >> 9) ? f : 1.17549435e-38f;
  return -xla_logf(-xla_logf(u));
}

// Single helper so rounding is identical everywhere.
__device__ __forceinline__ float score_one(uint32_t i, float lpv) {
#pragma clang fp contract(off)
  return lpv + gumbel_from_bits(tf_bits_partitionable(i));
}

// Per-vocab PRE-SHIFTED mantissa threshold: bits < thr_pre[v] => score < TCUT.
// bits >= thr<<9  <=>  (bits>>9) >= thr  (exact integer equivalence).
// thr = floor(exp(-exp(-(TCUT - lp[v]))) * 2^23) - 128 slack.
// Near the cut dg/du >= ~220 so 128 mantissa steps ≙ δg >= 3.4e-3, vs <= ~3e-5
// total float error in the expf / xla_logf chains -> 100x safety margin.
__global__ __launch_bounds__(256) void compute_thr(const float* __restrict__ sp,
                                                   uint32_t* __restrict__ thr_pre) {
  int v = blockIdx.x * 256 + threadIdx.x;
  if (v >= V_SZ) return;
  float lpv = xla_logf(sp[v]);
  float need = TCUT - lpv;                 // >= ~5.4 for this distribution
  float u = expf(-expf(-need));            // ideal inverse-Gumbel CDF at need
  int m = (int)floorf(u * 8388608.0f) - 128;
  thr_pre[v] = ((uint32_t)(m < 0 ? 0 : m)) << 9;
}

// One block per batch row. Hot loop = threefry + integer compare ONLY; scoring
// of the ~258 survivors happens in a post-pass. Exact-score guard falls back
// to the proven histogram path (never taken in practice).
__global__ __launch_bounds__(256) void select_negs(const float* __restrict__ sp,
                                                   const uint32_t* __restrict__ thr_pre,
                                                   int* __restrict__ negidx) {
  __shared__ uint32_t hist[NB];
  __shared__ float    cs[CAP];
  __shared__ int      ci[CAP];
  __shared__ uint32_t cb[CAP];
  __shared__ int      cnt;
  __shared__ int      cnt_hi;
  __shared__ int      cut;

  const int b = blockIdx.x;                             // 0..1023
  const uint32_t base = (uint32_t)b * (uint32_t)V_SZ;   // < 2^32

  if (threadIdx.x == 0) { cnt = 0; cnt_hi = 0; }
  __syncthreads();

  // Hot pass: threefry + compare. Survivors (~0.26%) just record (v, bits).
#pragma unroll 2
  for (int v = threadIdx.x; v < V_SZ; v += 256) {
    uint32_t bits = tf_bits_partitionable(base + (uint32_t)v);
    if (bits >= thr_pre[v]) {
      int k = atomicAdd(&cnt, 1);
      if (k < CAP) { ci[k] = v; cb[k] = bits; }
    }
  }
  __syncthreads();

  // Post-pass: exact scores for survivors (identical arithmetic to score_one).
  int n0 = min(cnt, CAP);
  for (int i = threadIdx.x; i < n0; i += 256) {
    float s = xla_logf(sp[ci[i]]) + gumbel_from_bits(cb[i]);
    cs[i] = s;
    if (s >= TCUT) atomicAdd(&cnt_hi, 1);
  }
  __syncthreads();

  // Guard: >=64 collected with exact s >= TCUT  =>  true 64th-best >= TCUT
  // => every true top-64 element passed the (conservative) filter and was
  // stored (cnt <= CAP). Ranks among the collected superset then equal
  // global ranks for all written entries.
  if (cnt <= CAP && cnt_hi >= NEG) {
    int n = cnt;
    for (int i = threadIdx.x; i < n; i += 256) {
      float si = cs[i]; int vi = ci[i];
      int rank = 0;
      for (int j = 0; j < n; ++j) {
        float sj = cs[j];
        rank += (sj > si) || (sj == si && ci[j] < vi);
      }
      if (rank < NEG) negidx[b * NEG + rank] = vi;
    }
    return;
  }

  // ---- Fallback: original exact histogram path (lp recomputed inline). ----
  const float LO = -28.0f, INVW = 51.2f;                // 2048 bins over [-28,12)
  for (int i = threadIdx.x; i < NB; i += 256) hist[i] = 0u;
  if (threadIdx.x == 0) cnt = 0;
  __syncthreads();

  for (int v = threadIdx.x; v < V_SZ; v += 256) {
    float s = score_one(base + (uint32_t)v, xla_logf(sp[v]));
    int bin = min(NB - 1, max(0, (int)((s - LO) * INVW)));
    atomicAdd(&hist[bin], 1u);
  }
  __syncthreads();

  if (threadIdx.x == 0) {
    uint32_t acc = 0; int c = NB - 1;
    for (; c > 0; --c) { acc += hist[c]; if (acc >= (uint32_t)NEG) break; }
    cut = c;
  }
  __syncthreads();
  const int cutb = cut;

  for (int v = threadIdx.x; v < V_SZ; v += 256) {
    float s = score_one(base + (uint32_t)v, xla_logf(sp[v]));
    int bin = min(NB - 1, max(0, (int)((s - LO) * INVW)));
    if (bin >= cutb) {
      int k = atomicAdd(&cnt, 1);
      if (k < CAP) { cs[k] = s; ci[k] = v; }
    }
  }
  __syncthreads();

  int n = min(cnt, CAP);
  for (int i = threadIdx.x; i < n; i += 256) {
    float si = cs[i]; int vi = ci[i];
    int rank = 0;
    for (int j = 0; j < n; ++j) {
      float sj = cs[j];
      rank += (sj > si) || (sj == si && ci[j] < vi);
    }
    if (rank < NEG) negidx[b * NEG + rank] = vi;
  }
}

// One wave per dot product. grid*4 waves == B*(C+NEG) == 86016 exactly.
// Each wave: 4 outstanding float4 loads/lane (2 KB row + 2 KB center row),
// 8 FMAs, 6 shuffles, 1 store. Center rows are L2-resident (84x reuse).
__global__ __launch_bounds__(256) void dots(const int* __restrict__ center_ids,
                                            const int* __restrict__ context_ids,
                                            const float* __restrict__ Wcen,
                                            const float* __restrict__ Wctx,
                                            const int* __restrict__ negidx,
                                            float* __restrict__ out) {
  const int wid  = blockIdx.x * 4 + (threadIdx.x >> 6);  // 0..86015
  const int lane = threadIdx.x & 63;
  const int b = wid / ITEMS;            // magic-mul division
  const int j = wid - b * ITEMS;

  const float4* crow = (const float4*)(Wcen + (size_t)center_ids[b] * D_SZ);
  const float* row;
  if (j < C_SZ) row = Wcen + (size_t)context_ids[b * C_SZ + j] * D_SZ;
  else          row = Wctx + (size_t)negidx[b * NEG + (j - C_SZ)] * D_SZ;
  const float4* r4 = (const float4*)row;

  float4 a0 = r4[lane * 2];
  float4 a1 = r4[lane * 2 + 1];
  float4 c0 = crow[lane * 2];
  float4 c1 = crow[lane * 2 + 1];

  float p = a0.x * c0.x + a0.y * c0.y + a0.z * c0.z + a0.w * c0.w +
            a1.x * c1.x + a1.y * c1.y + a1.z * c1.z + a1.w * c1.w;
  for (int off = 32; off; off >>= 1) p += __shfl_xor(p, off, 64);

  if (lane == 0) {
    if (j < C_SZ) out[b * C_SZ + j] = p;
    else          out[B_SZ * C_SZ + b * NEG + (j - C_SZ)] = p;
  }
}

extern "C" void kernel_launch(void* const* d_in, const int* in_sizes, int n_in,
                              void* d_out, int out_size, void* d_ws, size_t ws_size,
                              hipStream_t stream) {
  (void)in_sizes; (void)n_in; (void)out_size; (void)ws_size;
  const int*   center_ids  = (const int*)d_in[0];
  const int*   context_ids = (const int*)d_in[1];
  const float* Wcen        = (const float*)d_in[2];
  const float* Wctx        = (const float*)d_in[3];
  const float* sp          = (const float*)d_in[4];
  // d_in[5] = neg_sample (=64), compile-time constant here.

  uint32_t* thr_pre = (uint32_t*)d_ws;                   // V u32 (400 KB)
  int*      negidx  = (int*)((char*)d_ws + 512 * 1024);  // B*64 ints (256 KB)

  compute_thr<<<(V_SZ + 255) / 256, 256, 0, stream>>>(sp, thr_pre);
  select_negs<<<B_SZ,              256, 0, stream>>>(sp, thr_pre, negidx);
  dots       <<<(B_SZ * ITEMS) / 4, 256, 0, stream>>>(center_ids, context_ids,
                                                      Wcen, Wctx, negidx,
                                                      (float*)d_out);
}

// Round 4
// 619.818 us; speedup vs baseline: 1.8040x; 1.0567x over previous
//
#include <hip/hip_runtime.h>
#include <stdint.h>
#include <math.h>

#define V_SZ 100000
#define D_SZ 512
#define B_SZ 1024
#define C_SZ 20
#define NEG 64
#define NB 2048
#define CAP 512
#define TPB 512              // select_negs block size: 8 waves
#define ITEMS (C_SZ + NEG)   // 84
// -log(256): expected candidates/row = e^{-TCUT} * sum(sample_prob) = 256.
#define TCUT -5.5451774f

// ---- Cephes f32 log matching XLA-CPU GenerateVF32Log (FMA polynomial chain,
// separate mul/add tail). fp contract(off) so hipcc can't re-fuse differently.
__device__ __forceinline__ float xla_logf(float xin) {
#pragma clang fp contract(off)
  float x = fmaxf(xin, 1.17549435e-38f);            // clamp to min normal
  uint32_t bits = __float_as_uint(x);
  float e = (float)((int)(bits >> 23) - 127) + 1.0f;
  float m = __uint_as_float((bits & 0x807fffffu) | 0x3f000000u);  // [0.5,1)
  bool lt = m < 0.707106781186547524f;
  float tmp = lt ? m : 0.0f;
  m = m - 1.0f;
  e = e - (lt ? 1.0f : 0.0f);
  m = m + tmp;
  float z = m * m;
  float y = 7.0376836292E-2f;
  y = fmaf(y, m, -1.1514610310E-1f);
  y = fmaf(y, m, 1.1676998740E-1f);
  y = fmaf(y, m, -1.2420140846E-1f);
  y = fmaf(y, m, 1.4249322787E-1f);
  y = fmaf(y, m, -1.6668057665E-1f);
  y = fmaf(y, m, 2.0000714765E-1f);
  y = fmaf(y, m, -2.4999993993E-1f);
  y = fmaf(y, m, 3.3333331174E-1f);
  y = y * m;
  y = y * z;
  y = y + e * (-2.12194440e-4f);
  y = y - z * 0.5f;
  x = m + y;
  x = x + e * 0.693359375f;
  return x;
}

// ---- Threefry-2x32, 20 rounds, key = jax.random.key(42) -> (0, 42). ----
// Scalar version (used by fallback path only).
__device__ __forceinline__ void threefry2x32(uint32_t x0, uint32_t x1,
                                             uint32_t& o0, uint32_t& o1) {
  const uint32_t ks1 = 42u, ks2 = 0x1BD11BF0u;  // 0 ^ 42 ^ 0x1BD11BDA
#define TFR(r) { x0 += x1; x1 = __builtin_rotateleft32(x1, (r)); x1 ^= x0; }
  x0 += 0u; x1 += ks1;
  TFR(13) TFR(15) TFR(26) TFR(6)
  x0 += ks1; x1 += ks2 + 1u;
  TFR(17) TFR(29) TFR(16) TFR(24)
  x0 += ks2; x1 += 0u + 2u;
  TFR(13) TFR(15) TFR(26) TFR(6)
  x0 += 0u; x1 += ks1 + 3u;
  TFR(17) TFR(29) TFR(16) TFR(24)
  x0 += ks1; x1 += ks2 + 4u;
  TFR(13) TFR(15) TFR(26) TFR(6)
  x0 += ks2; x1 += 0u + 5u;
#undef TFR
  o0 = x0; o1 = x1;
}

__device__ __forceinline__ uint32_t tf_bits_partitionable(uint32_t i) {
  uint32_t o0, o1;
  threefry2x32(0u, i, o0, o1);
  return o0 ^ o1;
}

// 4-wide threefry: counters c0..c0+3, four INDEPENDENT dep chains fully
// unrolled (static indices -> registers, ILP=4). Same arithmetic per counter
// as threefry2x32(0, i); first key injection folded into init.
__device__ __forceinline__ void threefry4(uint32_t c0, uint32_t out[4]) {
  const uint32_t ks1 = 42u, ks2 = 0x1BD11BF0u;
  uint32_t a[4], b[4];
#pragma unroll
  for (int k = 0; k < 4; ++k) { a[k] = 0u; b[k] = c0 + (uint32_t)k + ks1; }
#define R4(r) { _Pragma("unroll") for (int k = 0; k < 4; ++k) { \
    a[k] += b[k]; b[k] = __builtin_rotateleft32(b[k], (r)); b[k] ^= a[k]; } }
#define INJ(i0, i1) { _Pragma("unroll") for (int k = 0; k < 4; ++k) { \
    a[k] += (i0); b[k] += (i1); } }
  R4(13) R4(15) R4(26) R4(6)
  INJ(ks1, ks2 + 1u)
  R4(17) R4(29) R4(16) R4(24)
  INJ(ks2, 0u + 2u)
  R4(13) R4(15) R4(26) R4(6)
  INJ(0u, ks1 + 3u)
  R4(17) R4(29) R4(16) R4(24)
  INJ(ks1, ks2 + 4u)
  R4(13) R4(15) R4(26) R4(6)
  INJ(ks2, 0u + 5u)
#undef R4
#undef INJ
#pragma unroll
  for (int k = 0; k < 4; ++k) out[k] = a[k] ^ b[k];
}

// u = (mbits>0) ? mbits*2^-23 : FLT_MIN ; g = -log(-log(u)).
__device__ __forceinline__ float gumbel_from_bits(uint32_t bits) {
#pragma clang fp contract(off)
  float f = __uint_as_float((bits >> 9) | 0x3f800000u) - 1.0f;
  float u = (bits >> 9) ? f : 1.17549435e-38f;
  return -xla_logf(-xla_logf(u));
}

__device__ __forceinline__ float score_one(uint32_t i, float lpv) {
#pragma clang fp contract(off)
  return lpv + gumbel_from_bits(tf_bits_partitionable(i));
}

// Per-vocab PRE-SHIFTED mantissa threshold: bits < thr_pre[v] => score < TCUT.
// thr = floor(exp(-exp(-(TCUT - lp[v]))) * 2^23) - 128 slack (~100x the float
// error of the expf/xla_logf chains near the cut, where dg/du >= ~220).
__global__ __launch_bounds__(256) void compute_thr(const float* __restrict__ sp,
                                                   uint32_t* __restrict__ thr_pre) {
  int v = blockIdx.x * 256 + threadIdx.x;
  if (v >= V_SZ) return;
  float lpv = xla_logf(sp[v]);
  float need = TCUT - lpv;                 // >= ~5.4 for this distribution
  float u = expf(-expf(-need));            // ideal inverse-Gumbel CDF at need
  int m = (int)floorf(u * 8388608.0f) - 128;
  thr_pre[v] = ((uint32_t)(m < 0 ? 0 : m)) << 9;
}

// One block (512 thr) per batch row. Hot loop: 4 consecutive elements/thread,
// 4-wide threefry + one uint4 threshold load + integer compares. Survivors
// (~258/row) are scored exactly in a post-pass; guard falls back to the
// proven histogram path (never taken in practice).
__global__ __launch_bounds__(TPB) void select_negs(const float* __restrict__ sp,
                                                   const uint32_t* __restrict__ thr_pre,
                                                   int* __restrict__ negidx) {
  __shared__ uint32_t hist[NB];
  __shared__ float    cs[CAP];
  __shared__ int      ci[CAP];
  __shared__ uint32_t cb[CAP];
  __shared__ int      cnt;
  __shared__ int      cnt_hi;
  __shared__ int      cut;

  const int b = blockIdx.x;                             // 0..1023
  const uint32_t base = (uint32_t)b * (uint32_t)V_SZ;   // < 2^32

  if (threadIdx.x == 0) { cnt = 0; cnt_hi = 0; }
  __syncthreads();

  // Hot pass. V_SZ % 4 == 0, so every 4-group is fully in-bounds.
  for (int v0 = threadIdx.x * 4; v0 < V_SZ; v0 += TPB * 4) {
    uint32_t bits[4];
    threefry4(base + (uint32_t)v0, bits);
    uint4 t4 = *(const uint4*)(thr_pre + v0);
    if (bits[0] >= t4.x) { int k = atomicAdd(&cnt, 1); if (k < CAP) { ci[k] = v0;     cb[k] = bits[0]; } }
    if (bits[1] >= t4.y) { int k = atomicAdd(&cnt, 1); if (k < CAP) { ci[k] = v0 + 1; cb[k] = bits[1]; } }
    if (bits[2] >= t4.z) { int k = atomicAdd(&cnt, 1); if (k < CAP) { ci[k] = v0 + 2; cb[k] = bits[2]; } }
    if (bits[3] >= t4.w) { int k = atomicAdd(&cnt, 1); if (k < CAP) { ci[k] = v0 + 3; cb[k] = bits[3]; } }
  }
  __syncthreads();

  // Post-pass: exact scores for survivors (identical arithmetic to score_one).
  int n0 = min(cnt, CAP);
  for (int i = threadIdx.x; i < n0; i += TPB) {
    float s = xla_logf(sp[ci[i]]) + gumbel_from_bits(cb[i]);
    cs[i] = s;
    if (s >= TCUT) atomicAdd(&cnt_hi, 1);
  }
  __syncthreads();

  // Guard: >=64 collected with exact s >= TCUT => true 64th-best >= TCUT =>
  // every true top-64 element passed the conservative filter and was stored.
  if (cnt <= CAP && cnt_hi >= NEG) {
    int n = cnt;
    for (int i = threadIdx.x; i < n; i += TPB) {
      float si = cs[i]; int vi = ci[i];
      int rank = 0;
      for (int j = 0; j < n; ++j) {
        float sj = cs[j];
        rank += (sj > si) || (sj == si && ci[j] < vi);
      }
      if (rank < NEG) negidx[b * NEG + rank] = vi;
    }
    return;
  }

  // ---- Fallback: original exact histogram path. ----
  const float LO = -28.0f, INVW = 51.2f;                // 2048 bins over [-28,12)
  for (int i = threadIdx.x; i < NB; i += TPB) hist[i] = 0u;
  if (threadIdx.x == 0) cnt = 0;
  __syncthreads();

  for (int v = threadIdx.x; v < V_SZ; v += TPB) {
    float s = score_one(base + (uint32_t)v, xla_logf(sp[v]));
    int bin = min(NB - 1, max(0, (int)((s - LO) * INVW)));
    atomicAdd(&hist[bin], 1u);
  }
  __syncthreads();

  if (threadIdx.x == 0) {
    uint32_t acc = 0; int c = NB - 1;
    for (; c > 0; --c) { acc += hist[c]; if (acc >= (uint32_t)NEG) break; }
    cut = c;
  }
  __syncthreads();
  const int cutb = cut;

  for (int v = threadIdx.x; v < V_SZ; v += TPB) {
    float s = score_one(base + (uint32_t)v, xla_logf(sp[v]));
    int bin = min(NB - 1, max(0, (int)((s - LO) * INVW)));
    if (bin >= cutb) {
      int k = atomicAdd(&cnt, 1);
      if (k < CAP) { cs[k] = s; ci[k] = v; }
    }
  }
  __syncthreads();

  int n = min(cnt, CAP);
  for (int i = threadIdx.x; i < n; i += TPB) {
    float si = cs[i]; int vi = ci[i];
    int rank = 0;
    for (int j = 0; j < n; ++j) {
      float sj = cs[j];
      rank += (sj > si) || (sj == si && ci[j] < vi);
    }
    if (rank < NEG) negidx[b * NEG + rank] = vi;
  }
}

// 4 dots per wave, all sharing one center row: 10 independent float4 loads
// per lane in flight (4 rows x 2 + center x 2), index math amortized 4x.
// q = wave id in [0, 21504); b = q/21; items j = 4*(q%21) + {0..3}.
// jj 0..4 -> all-context waves, jj 5..20 -> all-negative waves (no mixing).
__global__ __launch_bounds__(256) void dots(const int* __restrict__ center_ids,
                                            const int* __restrict__ context_ids,
                                            const float* __restrict__ Wcen,
                                            const float* __restrict__ Wctx,
                                            const int* __restrict__ negidx,
                                            float* __restrict__ out) {
  const int q    = blockIdx.x * 4 + (threadIdx.x >> 6);  // 0..21503
  const int lane = threadIdx.x & 63;
  const int b  = q / 21;                 // magic-mul division
  const int jj = q - b * 21;
  const int j0 = jj * 4;

  const float4* crow = (const float4*)(Wcen + (size_t)center_ids[b] * D_SZ);
  const float4* r4[4];
#pragma unroll
  for (int u = 0; u < 4; ++u) {
    int j = j0 + u;
    const float* row;
    if (j < C_SZ) row = Wcen + (size_t)context_ids[b * C_SZ + j] * D_SZ;
    else          row = Wctx + (size_t)negidx[b * NEG + (j - C_SZ)] * D_SZ;
    r4[u] = (const float4*)row;
  }

  float4 c0 = crow[lane * 2];
  float4 c1 = crow[lane * 2 + 1];
  float4 a0[4], a1[4];
#pragma unroll
  for (int u = 0; u < 4; ++u) { a0[u] = r4[u][lane * 2]; a1[u] = r4[u][lane * 2 + 1]; }

#pragma unroll
  for (int u = 0; u < 4; ++u) {
    float p = a0[u].x * c0.x + a0[u].y * c0.y + a0[u].z * c0.z + a0[u].w * c0.w +
              a1[u].x * c1.x + a1[u].y * c1.y + a1[u].z * c1.z + a1[u].w * c1.w;
    for (int off = 32; off; off >>= 1) p += __shfl_xor(p, off, 64);
    if (lane == 0) {
      int j = j0 + u;
      if (j < C_SZ) out[b * C_SZ + j] = p;
      else          out[B_SZ * C_SZ + b * NEG + (j - C_SZ)] = p;
    }
  }
}

extern "C" void kernel_launch(void* const* d_in, const int* in_sizes, int n_in,
                              void* d_out, int out_size, void* d_ws, size_t ws_size,
                              hipStream_t stream) {
  (void)in_sizes; (void)n_in; (void)out_size; (void)ws_size;
  const int*   center_ids  = (const int*)d_in[0];
  const int*   context_ids = (const int*)d_in[1];
  const float* Wcen        = (const float*)d_in[2];
  const float* Wctx        = (const float*)d_in[3];
  const float* sp          = (const float*)d_in[4];
  // d_in[5] = neg_sample (=64), compile-time constant here.

  uint32_t* thr_pre = (uint32_t*)d_ws;                   // V u32 (400 KB)
  int*      negidx  = (int*)((char*)d_ws + 512 * 1024);  // B*64 ints (256 KB)

  compute_thr<<<(V_SZ + 255) / 256, 256, 0, stream>>>(sp, thr_pre);
  select_negs<<<B_SZ,              TPB, 0, stream>>>(sp, thr_pre, negidx);
  dots       <<<(B_SZ * ITEMS) / 16, 256, 0, stream>>>(center_ids, context_ids,
                                                       Wcen, Wctx, negidx,
                                                       (float*)d_out);
}